// Round 7
// baseline (241.784 us; speedup 1.0000x reference)
//
#include <hip/hip_runtime.h>
#include <math.h>

#define DTC 0.1f

typedef _Float16 half8 __attribute__((ext_vector_type(8)));
typedef float f32x4 __attribute__((ext_vector_type(4)));

__device__ __forceinline__ float fast_tanh(float x) {
  const float e = __expf(2.f * x);
  const float r = __builtin_amdgcn_rcpf(e + 1.f);
  return fmaf(-2.f, r, 1.f);
}

// ================= precompute =================================================

// Wh = fp16(W) ; Wt = fp16(W^T) ; crm[l][j] = -0.09 * sum_k b_{l+2}[k] W_l[k][j]
__global__ __launch_bounds__(256) void k_prep(
    const float* __restrict__ W0, const float* __restrict__ W1,
    const float* __restrict__ W2, const float* __restrict__ W3,
    const float* __restrict__ b2, const float* __restrict__ b3,
    const float* __restrict__ b4,
    _Float16* __restrict__ Wh, _Float16* __restrict__ Wt,
    float* __restrict__ crm) {
  const float* Ws[4] = {W0, W1, W2, W3};
  const int bid = blockIdx.x, tid = threadIdx.x;
  if (bid < 128) {
    const int t = bid * 256 + tid;
    const float* W = Ws[(t * 8) >> 16];
    const int off = (t * 8) & 65535;
    const float4 a = *(const float4*)&W[off];
    const float4 b = *(const float4*)&W[off + 4];
    half8 h;
    h[0] = (_Float16)a.x; h[1] = (_Float16)a.y; h[2] = (_Float16)a.z; h[3] = (_Float16)a.w;
    h[4] = (_Float16)b.x; h[5] = (_Float16)b.y; h[6] = (_Float16)b.z; h[7] = (_Float16)b.w;
    *(half8*)&Wh[t * 8] = h;
  } else if (bid < 384) {
    __shared__ float sh[32][33];
    const int b2i = bid - 128;
    const int l = b2i >> 6, t64 = b2i & 63;
    const int r0 = (t64 >> 3) * 32, c0 = (t64 & 7) * 32;
    const float* W = Ws[l];
    const int i = tid >> 5, j = tid & 31;
#pragma unroll
    for (int p = 0; p < 4; ++p)
      sh[p * 8 + i][j] = W[(r0 + p * 8 + i) * 256 + c0 + j];
    __syncthreads();
#pragma unroll
    for (int p = 0; p < 4; ++p)
      Wt[l * 65536 + (c0 + p * 8 + i) * 256 + r0 + j] = (_Float16)sh[j][p * 8 + i];
  } else {
    const int l = bid - 384;
    const float* W = Ws[l];
    const float* b = (l == 0) ? b2 : (l == 1) ? b3 : b4;
    float s = 0.f;
#pragma unroll 8
    for (int k = 0; k < 256; ++k) s = fmaf(b[k], W[k * 256 + tid], s);
    crm[l * 256 + tid] = -0.09f * s;
  }
}

// C = scale*(A@B^T) [+ I - Eadd]   per layer (blockIdx.z), 256x256, fp16 rm out
__global__ __launch_bounds__(256) void k_smm3(const _Float16* __restrict__ A,
                                              const _Float16* __restrict__ B,
                                              const _Float16* __restrict__ Eadd,
                                              _Float16* __restrict__ C,
                                              float scale, int addI) {
  const int tid = threadIdx.x, wave = tid >> 6, lane = tid & 63;
  const int quad = lane >> 4, l16 = lane & 15;
  const int l = blockIdx.z;
  const _Float16* Al = A + (size_t)l * 65536;
  const _Float16* Bl = B + (size_t)l * 65536;
  _Float16* Cl = C + (size_t)l * 65536;
  const int m0 = blockIdx.y * 64 + wave * 16, n0 = blockIdx.x * 64;
  f32x4 acc[4] = {};
#pragma unroll
  for (int kt = 0; kt < 8; ++kt) {
    const half8 af = *(const half8*)&Al[(m0 + l16) * 256 + kt * 32 + quad * 8];
#pragma unroll
    for (int ni = 0; ni < 4; ++ni) {
      const half8 bf = *(const half8*)&Bl[(n0 + ni * 16 + l16) * 256 + kt * 32 + quad * 8];
      acc[ni] = __builtin_amdgcn_mfma_f32_16x16x32_f16(af, bf, acc[ni], 0, 0, 0);
    }
  }
#pragma unroll
  for (int ni = 0; ni < 4; ++ni)
#pragma unroll
    for (int r = 0; r < 4; ++r) {
      const int row = m0 + quad * 4 + r, col = n0 + ni * 16 + l16;
      float v = scale * acc[ni][r];
      if (addI) v += (row == col ? 1.f : 0.f) - (float)(Eadd + (size_t)l * 65536)[row * 256 + col];
      Cl[row * 256 + col] = (_Float16)v;
    }
}

// Destination-mapped coalesced packing of all B-frag weight buffers.
// chunk = 16B of 8 halves; packed idx = ((ntile*NKT+kt)*64 + lane)*8 + j
// holds B[n=ntile*16+(lane&15)][k=kt*32+(lane>>4)*8+j]
__global__ __launch_bounds__(256) void k_pack(
    const _Float16* __restrict__ Ph, const _Float16* __restrict__ Qt,
    const _Float16* __restrict__ Wt, const float* __restrict__ Wi,
    const float* __restrict__ Wo,
    _Float16* __restrict__ PQP, _Float16* __restrict__ RmP,
    _Float16* __restrict__ WiP, _Float16* __restrict__ WoP) {
  const int t = blockIdx.x * 256 + threadIdx.x;
  if (t < 65536) {  // PQP: NKT=16, kt<8 -> -P (sym), kt>=8 -> Qt
    const int l = t >> 14, c = t & 16383;
    const int ntile = c >> 10, kt = (c >> 6) & 15, lb = c & 63;
    const int n = ntile * 16 + (lb & 15);
    const int kq = (lb >> 4) * 8;
    half8 h;
    if (kt < 8) {
      h = *(const half8*)&Ph[(size_t)l * 65536 + n * 256 + kt * 32 + kq];
#pragma unroll
      for (int j = 0; j < 8; ++j) h[j] = -h[j];
    } else {
      h = *(const half8*)&Qt[(size_t)l * 65536 + n * 256 + (kt - 8) * 32 + kq];
    }
    *(half8*)&PQP[(size_t)t * 8] = h;
  } else if (t < 90112) {  // RmP: NKT=8, B[n][k] = -0.9*Wt[n][k]
    const int tt = t - 65536;
    const int l = tt >> 13, c = tt & 8191;
    const int ntile = c >> 9, kt = (c >> 6) & 7, lb = c & 63;
    const int n = ntile * 16 + (lb & 15);
    const int k0 = kt * 32 + (lb >> 4) * 8;
    half8 h = *(const half8*)&Wt[(size_t)l * 65536 + n * 256 + k0];
#pragma unroll
    for (int j = 0; j < 8; ++j) h[j] = (_Float16)(-0.9f * (float)h[j]);
    *(half8*)&RmP[(size_t)tt * 8] = h;
  } else if (t < 98304) {  // WiP: NKT=8, B[n][k] = Wi[n][k]
    const int c = t - 90112;
    const int ntile = c >> 9, kt = (c >> 6) & 7, lb = c & 63;
    const int n = ntile * 16 + (lb & 15);
    const int k0 = kt * 32 + (lb >> 4) * 8;
    const float4 a = *(const float4*)&Wi[n * 256 + k0];
    const float4 b = *(const float4*)&Wi[n * 256 + k0 + 4];
    half8 h;
    h[0] = (_Float16)a.x; h[1] = (_Float16)a.y; h[2] = (_Float16)a.z; h[3] = (_Float16)a.w;
    h[4] = (_Float16)b.x; h[5] = (_Float16)b.y; h[6] = (_Float16)b.z; h[7] = (_Float16)b.w;
    *(half8*)&WiP[(size_t)c * 8] = h;
  } else {  // WoP: NKT=8, classes padded to 16
    const int c = t - 98304;  // 0..511
    const int kt = c >> 6, lb = c & 63;
    const int n = lb & 15;
    const int k0 = kt * 32 + (lb >> 4) * 8;
    half8 h;
#pragma unroll
    for (int j = 0; j < 8; ++j) h[j] = (_Float16)((n < 10) ? Wo[n * 256 + k0 + j] : 0.f);
    *(half8*)&WoP[(size_t)c * 8] = h;
  }
}

// ================= fused persistent batch kernel =============================

__device__ __forceinline__ void lds_w16h(_Float16* base, int row, int col, _Float16 v) {
  const int chunk = (col >> 3) ^ (row & 7);
  *(_Float16*)((char*)base + row * 512 + (chunk << 4) + (col & 7) * 2) = v;
}

__device__ __forceinline__ _Float16 lds_r16h(const _Float16* base, int row, int col) {
  const int chunk = (col >> 3) ^ (row & 7);
  return *(const _Float16*)((const char*)base + row * 512 + (chunk << 4) + (col & 7) * 2);
}

// BIG wave tile 128 rows x 64 cols (mi=8, ni=4), 4 waves cover 128x256.
// Per-CU per-kt model: af-LDS = 32KB (250cyc @128B/c), bf-L2 = 16KB
// (292cyc @~56B/c) -> floor ~292cyc/kt per 128 rows, HALF of the R4
// config's 585 (R=64,C=32,16 waves: af 64KB + bf 32KB). Both traffic
// terms scale as 1/C and 1/R — only growing BOTH tile dims cuts the max.
template <int NKT, bool DUAL>
__device__ __forceinline__ void gemm_k(const _Float16* __restrict__ Bp,
                                       const _Float16* A1, const _Float16* A2,
                                       f32x4* acc, int wave, int lane, int quad, int l16) {
  half8 bf[3][4];
  auto loadB = [&](int kt, int s) {
#pragma unroll
    for (int ni = 0; ni < 4; ++ni)
      bf[s][ni] = *(const half8*)&Bp[(((wave * 4 + ni) * NKT + kt) * 64 + lane) * 8];
  };
  loadB(0, 0);
  loadB(1, 1);
#pragma unroll
  for (int kt = 0; kt < NKT; ++kt) {
    const int s = kt % 3;
    if (kt + 2 < NKT) loadB(kt + 2, (kt + 2) % 3);
    const _Float16* Ab = (DUAL && kt >= NKT / 2) ? A2 : A1;
    const int akt = DUAL ? (kt & (NKT / 2 - 1)) : kt;
    half8 af[8];
#pragma unroll
    for (int mi = 0; mi < 8; ++mi) {
      const int row = mi * 16 + l16;
      const int chunk = (akt * 4 + quad) ^ (row & 7);
      af[mi] = *(const half8*)((const char*)Ab + row * 512 + (chunk << 4));
    }
#pragma unroll
    for (int mi = 0; mi < 8; ++mi)
#pragma unroll
      for (int ni = 0; ni < 4; ++ni)
        acc[mi * 4 + ni] = __builtin_amdgcn_mfma_f32_16x16x32_f16(
            af[mi], bf[s][ni], acc[mi * 4 + ni], 0, 0, 0);
  }
}

// 128-row slab, 4 waves (256 thr, 1 wave/SIMD), LDS 128KB -> 1 block/CU.
// launch_bounds(256,1): reg cap 512 -> spills structurally impossible
// (R0-R6 lesson: every regression traced to allocator spills; WRITE_SIZE
// is the tell). ~225 live regs (acc 128 + bf ring 48 + af 32 + addr).
// All latency hiding is within-wave ILP: bf ring 2-ahead, 32 MFMA/kt cover.
__global__ __launch_bounds__(256, 1) void k_fused(
    const float* __restrict__ x, const _Float16* __restrict__ WiP,
    const _Float16* __restrict__ PQP, const _Float16* __restrict__ RmP,
    const _Float16* __restrict__ WoP, const float* __restrict__ bi,
    const float* __restrict__ b1, const float* __restrict__ b2,
    const float* __restrict__ b3, const float* __restrict__ b4,
    const float* __restrict__ crm, const float* __restrict__ bo,
    float* __restrict__ out) {
  __shared__ __align__(16) _Float16 A1[128 * 256];  // 64KB
  __shared__ __align__(16) _Float16 A2[128 * 256];  // 64KB
  const int tid = threadIdx.x;
  const int wave = tid >> 6, lane = tid & 63;
  const int quad = lane >> 4, l16 = lane & 15;
  const int m0 = blockIdx.x * 128;

  // ---- stage x: fp32 HBM -> fp16 swizzled LDS (A1), 128 rows ----
#pragma unroll 4
  for (int it = 0; it < 32; ++it) {
    const int idx = it * 256 + tid;
    const int row = idx >> 6, c4 = idx & 63;
    const float4 v = *(const float4*)&x[(size_t)(m0 + row) * 256 + c4 * 4];
    const int chunk = (c4 >> 1) ^ (row & 7), part = c4 & 1;
    _Float16* p = (_Float16*)((char*)A1 + row * 512 + (chunk << 4) + (part << 3));
    p[0] = (_Float16)v.x; p[1] = (_Float16)v.y; p[2] = (_Float16)v.z; p[3] = (_Float16)v.w;
  }
  __syncthreads();

  f32x4 acc[32];
  const f32x4 zero = {0.f, 0.f, 0.f, 0.f};

  // ---- GEMM0: z = x@WiT ; A1 = r1 = z+bi+0.1*b1 ; A2 = r2 = tanh(z+bi) ----
#pragma unroll
  for (int t = 0; t < 32; ++t) acc[t] = zero;
  gemm_k<8, false>(WiP, A1, A1, acc, wave, lane, quad, l16);
  __syncthreads();
#pragma unroll
  for (int ni = 0; ni < 4; ++ni) {
    const int col = wave * 64 + ni * 16 + l16;
    const float bic = bi[col], b1c = DTC * b1[col];
#pragma unroll
    for (int mi = 0; mi < 8; ++mi) {
#pragma unroll
      for (int r = 0; r < 4; ++r) {
        const float z = acc[mi * 4 + ni][r] + bic;
        const int row = mi * 16 + quad * 4 + r;
        lds_w16h(A1, row, col, (_Float16)(z + b1c));
        lds_w16h(A2, row, col, (_Float16)fast_tanh(z));
      }
    }
  }
  __syncthreads();

  // ---- 4 transport layers ----
#pragma unroll 1
  for (int l = 0; l < 4; ++l) {
    // u' = r1@Pm + r2@Q   (K=512)
#pragma unroll
    for (int t = 0; t < 32; ++t) acc[t] = zero;
    gemm_k<16, true>(PQP + (size_t)l * 131072, A1, A2, acc, wave, lane, quad, l16);
    __syncthreads();
    const float* bn = (l == 0) ? b2 : (l == 1) ? b3 : b4;
#pragma unroll
    for (int ni = 0; ni < 4; ++ni) {
      const int col = wave * 64 + ni * 16 + l16;
      const float bc = (l < 3) ? DTC * bn[col] : 0.f;
#pragma unroll
      for (int mi = 0; mi < 8; ++mi) {
#pragma unroll
        for (int r = 0; r < 4; ++r)
          lds_w16h(A1, mi * 16 + quad * 4 + r, col,
                   (_Float16)(acc[mi * 4 + ni][r] + bc));
      }
    }
    __syncthreads();
    if (l < 3) {
      // v' = r1@Rm - crm - r2 ; new r2 = (v' + 10 tanh u')/11
      // r2 re-read from A2; u' re-read from A1 (holds u'+bc) and de-biased.
#pragma unroll
      for (int t = 0; t < 32; ++t) acc[t] = zero;
      gemm_k<8, false>(RmP + (size_t)l * 65536, A1, A1, acc, wave, lane, quad, l16);
#pragma unroll
      for (int ni = 0; ni < 4; ++ni) {
        const int col = wave * 64 + ni * 16 + l16;
        const float cc = crm[l * 256 + col];
        const float bc = DTC * bn[col];
#pragma unroll
        for (int mi = 0; mi < 8; ++mi) {
#pragma unroll
          for (int r = 0; r < 4; ++r) {
            const int row = mi * 16 + quad * 4 + r;
            const float r2v = (float)lds_r16h(A2, row, col);
            const float ub = (float)lds_r16h(A1, row, col);
            const float vp = acc[mi * 4 + ni][r] - cc - r2v;
            const float nr2 = (vp + 10.f * fast_tanh(ub - bc)) * (1.f / 11.f);
            lds_w16h(A2, row, col, (_Float16)nr2);
          }
        }
      }
      __syncthreads();
    }
  }

  // ---- head: logits = z@Wo^T + bo (MFMA, 16-padded classes); softmax ----
  // 128 rows = 8 row-tiles; each of the 4 waves handles 2.
#pragma unroll
  for (int h = 0; h < 2; ++h) {
    const int rt = wave * 2 + h;
    f32x4 acch = zero;
#pragma unroll
    for (int kt = 0; kt < 8; ++kt) {
      const int row = rt * 16 + l16;
      const int chunk = (kt * 4 + quad) ^ (row & 7);
      const half8 af = *(const half8*)((const char*)A1 + row * 512 + (chunk << 4));
      const half8 bfr = *(const half8*)&WoP[(kt * 64 + lane) * 8];
      acch = __builtin_amdgcn_mfma_f32_16x16x32_f16(af, bfr, acch, 0, 0, 0);
    }
    const float bov = (l16 < 10) ? bo[l16] : -3.0e38f;
#pragma unroll
    for (int r = 0; r < 4; ++r) {
      float v = acch[r] + bov;
      float mx = v;
#pragma unroll
      for (int off = 1; off < 16; off <<= 1) mx = fmaxf(mx, __shfl_xor(mx, off, 64));
      const float e = __expf(v - mx);
      float s = e;
#pragma unroll
      for (int off = 1; off < 16; off <<= 1) s += __shfl_xor(s, off, 64);
      if (l16 < 10)
        out[(size_t)(m0 + rt * 16 + quad * 4 + r) * 10 + l16] = e * __builtin_amdgcn_rcpf(s);
    }
  }
}

// ================= launcher ==================================================

extern "C" void kernel_launch(void* const* d_in, const int* in_sizes, int n_in,
                              void* d_out, int out_size, void* d_ws, size_t ws_size,
                              hipStream_t stream) {
  const float* x  = (const float*)d_in[0];
  const float* Wi = (const float*)d_in[1];
  const float* bi = (const float*)d_in[2];
  const float* W[4] = {(const float*)d_in[3], (const float*)d_in[5],
                       (const float*)d_in[7], (const float*)d_in[9]};
  const float* b[4] = {(const float*)d_in[4], (const float*)d_in[6],
                       (const float*)d_in[8], (const float*)d_in[10]};
  const float* Wo = (const float*)d_in[11];
  const float* bo = (const float*)d_in[12];
  float* out = (float*)d_out;

  const int Bsz = in_sizes[0] / 256;  // 32768

  _Float16* hb = (_Float16*)d_ws;
  _Float16* WiP = hb;                   // 65536
  _Float16* WoP = hb + 65536;           // 4096
  _Float16* PQP = hb + 69632;           // 524288
  _Float16* RmP = hb + 593920;          // 196608
  _Float16* Wh  = hb + 790528;          // 262144
  _Float16* Wt  = hb + 1052672;         // 262144
  _Float16* Eh  = hb + 1314816;         // 262144
  _Float16* Ph  = hb + 1576960;         // 262144
  _Float16* Qt  = hb + 1839104;         // 262144
  float* crm = (float*)(hb + 2101248);  // 768 floats

  const dim3 g64(4, 4, 4);
  k_prep<<<387, 256, 0, stream>>>(W[0], W[1], W[2], W[3], b[1], b[2], b[3],
                                  Wh, Wt, crm);
  k_smm3<<<g64, 256, 0, stream>>>(Wh, Wh, nullptr, Eh, 0.01f, 0);  // E = DT^2 W W^T
  k_smm3<<<g64, 256, 0, stream>>>(Eh, Eh, Eh, Ph, 1.0f, 1);        // P = I - E + E^2
  k_smm3<<<g64, 256, 0, stream>>>(Ph, Wt, nullptr, Qt, DTC, 0);    // Qt = 0.1 P@W
  k_pack<<<386, 256, 0, stream>>>(Ph, Qt, Wt, Wi, Wo, PQP, RmP, WiP, WoP);

  k_fused<<<Bsz / 128, 256, 0, stream>>>(x, WiP, PQP, RmP, WoP, bi,
                                         b[0], b[1], b[2], b[3], crm, bo, out);
}

// Round 8
// 225.706 us; speedup vs baseline: 1.0712x; 1.0712x over previous
//
#include <hip/hip_runtime.h>
#include <math.h>

#define DTC 0.1f

typedef _Float16 half8 __attribute__((ext_vector_type(8)));
typedef float f32x4 __attribute__((ext_vector_type(4)));

__device__ __forceinline__ float fast_tanh(float x) {
  const float e = __expf(2.f * x);
  const float r = __builtin_amdgcn_rcpf(e + 1.f);
  return fmaf(-2.f, r, 1.f);
}

// ================= precompute =================================================

// Wh = fp16(W) ; Wt = fp16(W^T) ; crm[l][j] = -0.09 * sum_k b_{l+2}[k] W_l[k][j]
__global__ __launch_bounds__(256) void k_prep(
    const float* __restrict__ W0, const float* __restrict__ W1,
    const float* __restrict__ W2, const float* __restrict__ W3,
    const float* __restrict__ b2, const float* __restrict__ b3,
    const float* __restrict__ b4,
    _Float16* __restrict__ Wh, _Float16* __restrict__ Wt,
    float* __restrict__ crm) {
  const float* Ws[4] = {W0, W1, W2, W3};
  const int bid = blockIdx.x, tid = threadIdx.x;
  if (bid < 128) {
    const int t = bid * 256 + tid;
    const float* W = Ws[(t * 8) >> 16];
    const int off = (t * 8) & 65535;
    const float4 a = *(const float4*)&W[off];
    const float4 b = *(const float4*)&W[off + 4];
    half8 h;
    h[0] = (_Float16)a.x; h[1] = (_Float16)a.y; h[2] = (_Float16)a.z; h[3] = (_Float16)a.w;
    h[4] = (_Float16)b.x; h[5] = (_Float16)b.y; h[6] = (_Float16)b.z; h[7] = (_Float16)b.w;
    *(half8*)&Wh[t * 8] = h;
  } else if (bid < 384) {
    __shared__ float sh[32][33];
    const int b2i = bid - 128;
    const int l = b2i >> 6, t64 = b2i & 63;
    const int r0 = (t64 >> 3) * 32, c0 = (t64 & 7) * 32;
    const float* W = Ws[l];
    const int i = tid >> 5, j = tid & 31;
#pragma unroll
    for (int p = 0; p < 4; ++p)
      sh[p * 8 + i][j] = W[(r0 + p * 8 + i) * 256 + c0 + j];
    __syncthreads();
#pragma unroll
    for (int p = 0; p < 4; ++p)
      Wt[l * 65536 + (c0 + p * 8 + i) * 256 + r0 + j] = (_Float16)sh[j][p * 8 + i];
  } else {
    const int l = bid - 384;
    const float* W = Ws[l];
    const float* b = (l == 0) ? b2 : (l == 1) ? b3 : b4;
    float s = 0.f;
#pragma unroll 8
    for (int k = 0; k < 256; ++k) s = fmaf(b[k], W[k * 256 + tid], s);
    crm[l * 256 + tid] = -0.09f * s;
  }
}

// C = scale*(A@B^T) [+ I - Eadd]   per layer (blockIdx.z), 256x256, fp16 rm out
__global__ __launch_bounds__(256) void k_smm3(const _Float16* __restrict__ A,
                                              const _Float16* __restrict__ B,
                                              const _Float16* __restrict__ Eadd,
                                              _Float16* __restrict__ C,
                                              float scale, int addI) {
  const int tid = threadIdx.x, wave = tid >> 6, lane = tid & 63;
  const int quad = lane >> 4, l16 = lane & 15;
  const int l = blockIdx.z;
  const _Float16* Al = A + (size_t)l * 65536;
  const _Float16* Bl = B + (size_t)l * 65536;
  _Float16* Cl = C + (size_t)l * 65536;
  const int m0 = blockIdx.y * 64 + wave * 16, n0 = blockIdx.x * 64;
  f32x4 acc[4] = {};
#pragma unroll
  for (int kt = 0; kt < 8; ++kt) {
    const half8 af = *(const half8*)&Al[(m0 + l16) * 256 + kt * 32 + quad * 8];
#pragma unroll
    for (int ni = 0; ni < 4; ++ni) {
      const half8 bf = *(const half8*)&Bl[(n0 + ni * 16 + l16) * 256 + kt * 32 + quad * 8];
      acc[ni] = __builtin_amdgcn_mfma_f32_16x16x32_f16(af, bf, acc[ni], 0, 0, 0);
    }
  }
#pragma unroll
  for (int ni = 0; ni < 4; ++ni)
#pragma unroll
    for (int r = 0; r < 4; ++r) {
      const int row = m0 + quad * 4 + r, col = n0 + ni * 16 + l16;
      float v = scale * acc[ni][r];
      if (addI) v += (row == col ? 1.f : 0.f) - (float)(Eadd + (size_t)l * 65536)[row * 256 + col];
      Cl[row * 256 + col] = (_Float16)v;
    }
}

// Destination-mapped coalesced packing of all B-frag weight buffers.
// chunk = 16B of 8 halves; packed idx = ((ntile*NKT+kt)*64 + lane)*8 + j
// holds B[n=ntile*16+(lane&15)][k=kt*32+(lane>>4)*8+j]
__global__ __launch_bounds__(256) void k_pack(
    const _Float16* __restrict__ Ph, const _Float16* __restrict__ Qt,
    const _Float16* __restrict__ Wt, const float* __restrict__ Wi,
    const float* __restrict__ Wo,
    _Float16* __restrict__ PQP, _Float16* __restrict__ RmP,
    _Float16* __restrict__ WiP, _Float16* __restrict__ WoP) {
  const int t = blockIdx.x * 256 + threadIdx.x;
  if (t < 65536) {  // PQP: NKT=16, kt<8 -> -P (sym), kt>=8 -> Qt
    const int l = t >> 14, c = t & 16383;
    const int ntile = c >> 10, kt = (c >> 6) & 15, lb = c & 63;
    const int n = ntile * 16 + (lb & 15);
    const int kq = (lb >> 4) * 8;
    half8 h;
    if (kt < 8) {
      h = *(const half8*)&Ph[(size_t)l * 65536 + n * 256 + kt * 32 + kq];
#pragma unroll
      for (int j = 0; j < 8; ++j) h[j] = -h[j];
    } else {
      h = *(const half8*)&Qt[(size_t)l * 65536 + n * 256 + (kt - 8) * 32 + kq];
    }
    *(half8*)&PQP[(size_t)t * 8] = h;
  } else if (t < 90112) {  // RmP: NKT=8, B[n][k] = -0.9*Wt[n][k]
    const int tt = t - 65536;
    const int l = tt >> 13, c = tt & 8191;
    const int ntile = c >> 9, kt = (c >> 6) & 7, lb = c & 63;
    const int n = ntile * 16 + (lb & 15);
    const int k0 = kt * 32 + (lb >> 4) * 8;
    half8 h = *(const half8*)&Wt[(size_t)l * 65536 + n * 256 + k0];
#pragma unroll
    for (int j = 0; j < 8; ++j) h[j] = (_Float16)(-0.9f * (float)h[j]);
    *(half8*)&RmP[(size_t)tt * 8] = h;
  } else if (t < 98304) {  // WiP: NKT=8, B[n][k] = Wi[n][k]
    const int c = t - 90112;
    const int ntile = c >> 9, kt = (c >> 6) & 7, lb = c & 63;
    const int n = ntile * 16 + (lb & 15);
    const int k0 = kt * 32 + (lb >> 4) * 8;
    const float4 a = *(const float4*)&Wi[n * 256 + k0];
    const float4 b = *(const float4*)&Wi[n * 256 + k0 + 4];
    half8 h;
    h[0] = (_Float16)a.x; h[1] = (_Float16)a.y; h[2] = (_Float16)a.z; h[3] = (_Float16)a.w;
    h[4] = (_Float16)b.x; h[5] = (_Float16)b.y; h[6] = (_Float16)b.z; h[7] = (_Float16)b.w;
    *(half8*)&WiP[(size_t)c * 8] = h;
  } else {  // WoP: NKT=8, classes padded to 16
    const int c = t - 98304;  // 0..511
    const int kt = c >> 6, lb = c & 63;
    const int n = lb & 15;
    const int k0 = kt * 32 + (lb >> 4) * 8;
    half8 h;
#pragma unroll
    for (int j = 0; j < 8; ++j) h[j] = (_Float16)((n < 10) ? Wo[n * 256 + k0 + j] : 0.f);
    *(half8*)&WoP[(size_t)c * 8] = h;
  }
}

// ================= fused persistent batch kernel =============================

__device__ __forceinline__ void lds_w16h(_Float16* base, int row, int col, _Float16 v) {
  const int chunk = (col >> 3) ^ (row & 7);
  *(_Float16*)((char*)base + row * 512 + (chunk << 4) + (col & 7) * 2) = v;
}

__device__ __forceinline__ _Float16 lds_r16h(const _Float16* base, int row, int col) {
  const int chunk = (col >> 3) ^ (row & 7);
  return *(const _Float16*)((const char*)base + row * 512 + (chunk << 4) + (col & 7) * 2);
}

// R4-champion geometry: wave tile 64x32 (mi=4, ni=2), 8 waves, 64-row slab.
template <int NKT, bool DUAL>
__device__ __forceinline__ void gemm_k(const _Float16* __restrict__ Bp,
                                       const _Float16* A1, const _Float16* A2,
                                       f32x4* acc, int wave, int lane, int quad, int l16) {
  half8 bf[3][2];
  auto loadB = [&](int kt, int s) {
#pragma unroll
    for (int ni = 0; ni < 2; ++ni)
      bf[s][ni] = *(const half8*)&Bp[(((wave * 2 + ni) * NKT + kt) * 64 + lane) * 8];
  };
  loadB(0, 0);
  loadB(1, 1);
#pragma unroll
  for (int kt = 0; kt < NKT; ++kt) {
    const int s = kt % 3;
    if (kt + 2 < NKT) loadB(kt + 2, (kt + 2) % 3);
    const _Float16* Ab = (DUAL && kt >= NKT / 2) ? A2 : A1;
    const int akt = DUAL ? (kt & (NKT / 2 - 1)) : kt;
    half8 af[4];
#pragma unroll
    for (int mi = 0; mi < 4; ++mi) {
      const int row = mi * 16 + l16;
      const int chunk = (akt * 4 + quad) ^ (row & 7);
      af[mi] = *(const half8*)((const char*)Ab + row * 512 + (chunk << 4));
    }
#pragma unroll
    for (int mi = 0; mi < 4; ++mi)
#pragma unroll
      for (int ni = 0; ni < 2; ++ni)
        acc[mi * 2 + ni] = __builtin_amdgcn_mfma_f32_16x16x32_f16(
            af[mi], bf[s][ni], acc[mi * 2 + ni], 0, 0, 0);
  }
}

// MERGED layer GEMM (l<3): one 8-kt pass computes BOTH
//   u' = r1@(-P)^T + r2@Qt^T   (acc_u)
//   v'gemm = r1@(-0.9 Wt)^T    (acc_v)
// sharing the af fragments (af reads 96 -> 64 per wave per layer, -33%),
// one barrier and one epilogue pass instead of two each. 24 MFMA/kt cover
// the 6-load 2-slot bf ring. Registers: 32+32 acc + 48 bf + 32 af ~ 210
// < the 256 cap of (512,2) — spill-free per the R4-established budget.
__device__ __forceinline__ void gemm_uv(const _Float16* __restrict__ Pp,
                                        const _Float16* __restrict__ Rp,
                                        const _Float16* A1, const _Float16* A2,
                                        f32x4* accu, f32x4* accv,
                                        int wave, int lane, int quad, int l16) {
  half8 bfP[2][2], bfQ[2][2], bfR[2][2];
  auto loadB = [&](int kt, int s) {
#pragma unroll
    for (int ni = 0; ni < 2; ++ni) {
      const int nt = wave * 2 + ni;
      bfP[s][ni] = *(const half8*)&Pp[((nt * 16 + kt) * 64 + lane) * 8];
      bfQ[s][ni] = *(const half8*)&Pp[((nt * 16 + kt + 8) * 64 + lane) * 8];
      bfR[s][ni] = *(const half8*)&Rp[((nt * 8 + kt) * 64 + lane) * 8];
    }
  };
  loadB(0, 0);
#pragma unroll
  for (int kt = 0; kt < 8; ++kt) {
    const int s = kt & 1;
    if (kt + 1 < 8) loadB(kt + 1, (kt + 1) & 1);
    half8 af1[4], af2[4];
#pragma unroll
    for (int mi = 0; mi < 4; ++mi) {
      const int row = mi * 16 + l16;
      const int chunk = (kt * 4 + quad) ^ (row & 7);
      af1[mi] = *(const half8*)((const char*)A1 + row * 512 + (chunk << 4));
      af2[mi] = *(const half8*)((const char*)A2 + row * 512 + (chunk << 4));
    }
#pragma unroll
    for (int mi = 0; mi < 4; ++mi)
#pragma unroll
      for (int ni = 0; ni < 2; ++ni) {
        accu[mi * 2 + ni] = __builtin_amdgcn_mfma_f32_16x16x32_f16(
            af1[mi], bfP[s][ni], accu[mi * 2 + ni], 0, 0, 0);
        accu[mi * 2 + ni] = __builtin_amdgcn_mfma_f32_16x16x32_f16(
            af2[mi], bfQ[s][ni], accu[mi * 2 + ni], 0, 0, 0);
        accv[mi * 2 + ni] = __builtin_amdgcn_mfma_f32_16x16x32_f16(
            af1[mi], bfR[s][ni], accv[mi * 2 + ni], 0, 0, 0);
      }
  }
}

// 64-row slab, 8 waves, 2 blocks/CU (LDS-bound). launch_bounds(512,2):
// VGPR cap 256 — the only spill-free operating point (WRITE_SIZE is the tell).
__global__ __launch_bounds__(512, 2) void k_fused(
    const float* __restrict__ x, const _Float16* __restrict__ WiP,
    const _Float16* __restrict__ PQP, const _Float16* __restrict__ RmP,
    const _Float16* __restrict__ WoP, const float* __restrict__ bi,
    const float* __restrict__ b1, const float* __restrict__ b2,
    const float* __restrict__ b3, const float* __restrict__ b4,
    const float* __restrict__ crm, const float* __restrict__ bo,
    float* __restrict__ out) {
  __shared__ __align__(16) _Float16 A1[64 * 256];
  __shared__ __align__(16) _Float16 A2[64 * 256];
  const int tid = threadIdx.x;
  const int wave = tid >> 6, lane = tid & 63;
  const int quad = lane >> 4, l16 = lane & 15;
  const int m0 = blockIdx.x * 64;

  // ---- stage x: fp32 HBM -> fp16 swizzled LDS (A1) ----
#pragma unroll
  for (int it = 0; it < 8; ++it) {
    const int idx = it * 512 + tid;
    const int row = idx >> 6, c4 = idx & 63;
    const float4 v = *(const float4*)&x[(size_t)(m0 + row) * 256 + c4 * 4];
    const int chunk = (c4 >> 1) ^ (row & 7), part = c4 & 1;
    _Float16* p = (_Float16*)((char*)A1 + row * 512 + (chunk << 4) + (part << 3));
    p[0] = (_Float16)v.x; p[1] = (_Float16)v.y; p[2] = (_Float16)v.z; p[3] = (_Float16)v.w;
  }
  __syncthreads();

  f32x4 accu[8], accv[8];
  const f32x4 zero = {0.f, 0.f, 0.f, 0.f};

  // ---- GEMM0: z = x@WiT ; A1 = r1 = z+bi+0.1*b1 ; A2 = r2 = tanh(z+bi) ----
#pragma unroll
  for (int t = 0; t < 8; ++t) accu[t] = zero;
  gemm_k<8, false>(WiP, A1, A1, accu, wave, lane, quad, l16);
  __syncthreads();
#pragma unroll
  for (int ni = 0; ni < 2; ++ni) {
    const int col = wave * 32 + ni * 16 + l16;
    const float bic = bi[col], b1c = DTC * b1[col];
#pragma unroll
    for (int mi = 0; mi < 4; ++mi) {
#pragma unroll
      for (int r = 0; r < 4; ++r) {
        const float z = accu[mi * 2 + ni][r] + bic;
        const int row = mi * 16 + quad * 4 + r;
        lds_w16h(A1, row, col, (_Float16)(z + b1c));
        lds_w16h(A2, row, col, (_Float16)fast_tanh(z));
      }
    }
  }
  __syncthreads();

  // ---- layers 0..2: merged u'/v' GEMM + single epilogue ----
#pragma unroll 1
  for (int l = 0; l < 3; ++l) {
#pragma unroll
    for (int t = 0; t < 8; ++t) { accu[t] = zero; accv[t] = zero; }
    gemm_uv(PQP + (size_t)l * 131072, RmP + (size_t)l * 65536,
            A1, A2, accu, accv, wave, lane, quad, l16);
    __syncthreads();
    const float* bn = (l == 0) ? b2 : (l == 1) ? b3 : b4;
#pragma unroll
    for (int ni = 0; ni < 2; ++ni) {
      const int col = wave * 32 + ni * 16 + l16;
      const float cc = crm[l * 256 + col];
      const float bc = DTC * bn[col];
#pragma unroll
      for (int mi = 0; mi < 4; ++mi) {
#pragma unroll
        for (int r = 0; r < 4; ++r) {
          const int row = mi * 16 + quad * 4 + r;
          const float u = accu[mi * 2 + ni][r];
          const float r2v = (float)lds_r16h(A2, row, col);  // old r2 (own elem)
          const float vp = accv[mi * 2 + ni][r] - cc - r2v;
          const float nr2 = (vp + 10.f * fast_tanh(u)) * (1.f / 11.f);
          lds_w16h(A1, row, col, (_Float16)(u + bc));  // r1 for next layer
          lds_w16h(A2, row, col, (_Float16)nr2);       // r2 for next layer
        }
      }
    }
    __syncthreads();
  }

  // ---- layer 3: u' only (K=512 dual GEMM), no v' needed ----
#pragma unroll
  for (int t = 0; t < 8; ++t) accu[t] = zero;
  gemm_k<16, true>(PQP + (size_t)3 * 131072, A1, A2, accu, wave, lane, quad, l16);
  __syncthreads();
#pragma unroll
  for (int ni = 0; ni < 2; ++ni) {
    const int col = wave * 32 + ni * 16 + l16;
#pragma unroll
    for (int mi = 0; mi < 4; ++mi) {
#pragma unroll
      for (int r = 0; r < 4; ++r)
        lds_w16h(A1, mi * 16 + quad * 4 + r, col, (_Float16)accu[mi * 2 + ni][r]);
    }
  }
  __syncthreads();

  // ---- head: logits = z@Wo^T + bo (MFMA, 16-padded classes); softmax ----
  if (wave < 4) {
    f32x4 acch = zero;
#pragma unroll
    for (int kt = 0; kt < 8; ++kt) {
      const int row = wave * 16 + l16;
      const int chunk = (kt * 4 + quad) ^ (row & 7);
      const half8 af = *(const half8*)((const char*)A1 + row * 512 + (chunk << 4));
      const half8 bfr = *(const half8*)&WoP[(kt * 64 + lane) * 8];
      acch = __builtin_amdgcn_mfma_f32_16x16x32_f16(af, bfr, acch, 0, 0, 0);
    }
    const float bov = (l16 < 10) ? bo[l16] : -3.0e38f;
#pragma unroll
    for (int r = 0; r < 4; ++r) {
      float v = acch[r] + bov;
      float mx = v;
#pragma unroll
      for (int off = 1; off < 16; off <<= 1) mx = fmaxf(mx, __shfl_xor(mx, off, 64));
      const float e = __expf(v - mx);
      float s = e;
#pragma unroll
      for (int off = 1; off < 16; off <<= 1) s += __shfl_xor(s, off, 64);
      if (l16 < 10)
        out[(size_t)(m0 + wave * 16 + quad * 4 + r) * 10 + l16] = e * __builtin_amdgcn_rcpf(s);
    }
  }
}

// ================= launcher ==================================================

extern "C" void kernel_launch(void* const* d_in, const int* in_sizes, int n_in,
                              void* d_out, int out_size, void* d_ws, size_t ws_size,
                              hipStream_t stream) {
  const float* x  = (const float*)d_in[0];
  const float* Wi = (const float*)d_in[1];
  const float* bi = (const float*)d_in[2];
  const float* W[4] = {(const float*)d_in[3], (const float*)d_in[5],
                       (const float*)d_in[7], (const float*)d_in[9]};
  const float* b[4] = {(const float*)d_in[4], (const float*)d_in[6],
                       (const float*)d_in[8], (const float*)d_in[10]};
  const float* Wo = (const float*)d_in[11];
  const float* bo = (const float*)d_in[12];
  float* out = (float*)d_out;

  const int Bsz = in_sizes[0] / 256;  // 32768

  _Float16* hb = (_Float16*)d_ws;
  _Float16* WiP = hb;                   // 65536
  _Float16* WoP = hb + 65536;           // 4096
  _Float16* PQP = hb + 69632;           // 524288
  _Float16* RmP = hb + 593920;          // 196608
  _Float16* Wh  = hb + 790528;          // 262144
  _Float16* Wt  = hb + 1052672;         // 262144
  _Float16* Eh  = hb + 1314816;         // 262144
  _Float16* Ph  = hb + 1576960;         // 262144
  _Float16* Qt  = hb + 1839104;         // 262144
  float* crm = (float*)(hb + 2101248);  // 768 floats

  const dim3 g64(4, 4, 4);
  k_prep<<<387, 256, 0, stream>>>(W[0], W[1], W[2], W[3], b[1], b[2], b[3],
                                  Wh, Wt, crm);
  k_smm3<<<g64, 256, 0, stream>>>(Wh, Wh, nullptr, Eh, 0.01f, 0);  // E = DT^2 W W^T
  k_smm3<<<g64, 256, 0, stream>>>(Eh, Eh, Eh, Ph, 1.0f, 1);        // P = I - E + E^2
  k_smm3<<<g64, 256, 0, stream>>>(Ph, Wt, nullptr, Qt, DTC, 0);    // Qt = 0.1 P@W
  k_pack<<<386, 256, 0, stream>>>(Ph, Qt, Wt, Wi, Wo, PQP, RmP, WiP, WoP);

  k_fused<<<Bsz / 64, 512, 0, stream>>>(x, WiP, PQP, RmP, WoP, bi,
                                        b[0], b[1], b[2], b[3], crm, bo, out);
}

// Round 9
// 203.967 us; speedup vs baseline: 1.1854x; 1.1066x over previous
//
#include <hip/hip_runtime.h>
#include <math.h>

#define DTC 0.1f

typedef _Float16 half8 __attribute__((ext_vector_type(8)));
typedef _Float16 half4v __attribute__((ext_vector_type(4)));
typedef float f32x4 __attribute__((ext_vector_type(4)));
typedef float f32x2 __attribute__((ext_vector_type(2)));

__device__ __forceinline__ float fast_tanh(float x) {
  const float e = __expf(2.f * x);
  const float r = __builtin_amdgcn_rcpf(e + 1.f);
  return fmaf(-2.f, r, 1.f);
}

// ================= precompute =================================================

// Wh = fp16(W) ; Wt = fp16(W^T) ; crm[l][j] = -0.09 * sum_k b_{l+2}[k] W_l[k][j]
__global__ __launch_bounds__(256) void k_prep(
    const float* __restrict__ W0, const float* __restrict__ W1,
    const float* __restrict__ W2, const float* __restrict__ W3,
    const float* __restrict__ b2, const float* __restrict__ b3,
    const float* __restrict__ b4,
    _Float16* __restrict__ Wh, _Float16* __restrict__ Wt,
    float* __restrict__ crm) {
  const float* Ws[4] = {W0, W1, W2, W3};
  const int bid = blockIdx.x, tid = threadIdx.x;
  if (bid < 128) {
    const int t = bid * 256 + tid;
    const float* W = Ws[(t * 8) >> 16];
    const int off = (t * 8) & 65535;
    const float4 a = *(const float4*)&W[off];
    const float4 b = *(const float4*)&W[off + 4];
    half8 h;
    h[0] = (_Float16)a.x; h[1] = (_Float16)a.y; h[2] = (_Float16)a.z; h[3] = (_Float16)a.w;
    h[4] = (_Float16)b.x; h[5] = (_Float16)b.y; h[6] = (_Float16)b.z; h[7] = (_Float16)b.w;
    *(half8*)&Wh[t * 8] = h;
  } else if (bid < 384) {
    __shared__ float sh[32][33];
    const int b2i = bid - 128;
    const int l = b2i >> 6, t64 = b2i & 63;
    const int r0 = (t64 >> 3) * 32, c0 = (t64 & 7) * 32;
    const float* W = Ws[l];
    const int i = tid >> 5, j = tid & 31;
#pragma unroll
    for (int p = 0; p < 4; ++p)
      sh[p * 8 + i][j] = W[(r0 + p * 8 + i) * 256 + c0 + j];
    __syncthreads();
#pragma unroll
    for (int p = 0; p < 4; ++p)
      Wt[l * 65536 + (c0 + p * 8 + i) * 256 + r0 + j] = (_Float16)sh[j][p * 8 + i];
  } else {
    const int l = bid - 384;
    const float* W = Ws[l];
    const float* b = (l == 0) ? b2 : (l == 1) ? b3 : b4;
    float s = 0.f;
#pragma unroll 8
    for (int k = 0; k < 256; ++k) s = fmaf(b[k], W[k * 256 + tid], s);
    crm[l * 256 + tid] = -0.09f * s;
  }
}

// C = scale*(A@B^T) [+ I - Eadd]   per layer (blockIdx.z), 256x256, fp16 rm out
__global__ __launch_bounds__(256) void k_smm3(const _Float16* __restrict__ A,
                                              const _Float16* __restrict__ B,
                                              const _Float16* __restrict__ Eadd,
                                              _Float16* __restrict__ C,
                                              float scale, int addI) {
  const int tid = threadIdx.x, wave = tid >> 6, lane = tid & 63;
  const int quad = lane >> 4, l16 = lane & 15;
  const int l = blockIdx.z;
  const _Float16* Al = A + (size_t)l * 65536;
  const _Float16* Bl = B + (size_t)l * 65536;
  _Float16* Cl = C + (size_t)l * 65536;
  const int m0 = blockIdx.y * 64 + wave * 16, n0 = blockIdx.x * 64;
  f32x4 acc[4] = {};
#pragma unroll
  for (int kt = 0; kt < 8; ++kt) {
    const half8 af = *(const half8*)&Al[(m0 + l16) * 256 + kt * 32 + quad * 8];
#pragma unroll
    for (int ni = 0; ni < 4; ++ni) {
      const half8 bf = *(const half8*)&Bl[(n0 + ni * 16 + l16) * 256 + kt * 32 + quad * 8];
      acc[ni] = __builtin_amdgcn_mfma_f32_16x16x32_f16(af, bf, acc[ni], 0, 0, 0);
    }
  }
#pragma unroll
  for (int ni = 0; ni < 4; ++ni)
#pragma unroll
    for (int r = 0; r < 4; ++r) {
      const int row = m0 + quad * 4 + r, col = n0 + ni * 16 + l16;
      float v = scale * acc[ni][r];
      if (addI) v += (row == col ? 1.f : 0.f) - (float)(Eadd + (size_t)l * 65536)[row * 256 + col];
      Cl[row * 256 + col] = (_Float16)v;
    }
}

// Destination-mapped coalesced packing of all B-frag weight buffers.
// chunk = 16B of 8 halves; packed idx = ((ntile*NKT+kt)*64 + lane)*8 + j
// holds B[n=ntile*16+(lane&15)][k=kt*32+(lane>>4)*8+j]
__global__ __launch_bounds__(256) void k_pack(
    const _Float16* __restrict__ Ph, const _Float16* __restrict__ Qt,
    const _Float16* __restrict__ Wt, const float* __restrict__ Wi,
    const float* __restrict__ Wo,
    _Float16* __restrict__ PQP, _Float16* __restrict__ RmP,
    _Float16* __restrict__ WiP, _Float16* __restrict__ WoP) {
  const int t = blockIdx.x * 256 + threadIdx.x;
  if (t < 65536) {  // PQP: NKT=16, kt<8 -> -P (sym), kt>=8 -> Qt
    const int l = t >> 14, c = t & 16383;
    const int ntile = c >> 10, kt = (c >> 6) & 15, lb = c & 63;
    const int n = ntile * 16 + (lb & 15);
    const int kq = (lb >> 4) * 8;
    half8 h;
    if (kt < 8) {
      h = *(const half8*)&Ph[(size_t)l * 65536 + n * 256 + kt * 32 + kq];
#pragma unroll
      for (int j = 0; j < 8; ++j) h[j] = -h[j];
    } else {
      h = *(const half8*)&Qt[(size_t)l * 65536 + n * 256 + (kt - 8) * 32 + kq];
    }
    *(half8*)&PQP[(size_t)t * 8] = h;
  } else if (t < 90112) {  // RmP: NKT=8, B[n][k] = -0.9*Wt[n][k]
    const int tt = t - 65536;
    const int l = tt >> 13, c = tt & 8191;
    const int ntile = c >> 9, kt = (c >> 6) & 7, lb = c & 63;
    const int n = ntile * 16 + (lb & 15);
    const int k0 = kt * 32 + (lb >> 4) * 8;
    half8 h = *(const half8*)&Wt[(size_t)l * 65536 + n * 256 + k0];
#pragma unroll
    for (int j = 0; j < 8; ++j) h[j] = (_Float16)(-0.9f * (float)h[j]);
    *(half8*)&RmP[(size_t)tt * 8] = h;
  } else if (t < 98304) {  // WiP: NKT=8, B[n][k] = Wi[n][k]
    const int c = t - 90112;
    const int ntile = c >> 9, kt = (c >> 6) & 7, lb = c & 63;
    const int n = ntile * 16 + (lb & 15);
    const int k0 = kt * 32 + (lb >> 4) * 8;
    const float4 a = *(const float4*)&Wi[n * 256 + k0];
    const float4 b = *(const float4*)&Wi[n * 256 + k0 + 4];
    half8 h;
    h[0] = (_Float16)a.x; h[1] = (_Float16)a.y; h[2] = (_Float16)a.z; h[3] = (_Float16)a.w;
    h[4] = (_Float16)b.x; h[5] = (_Float16)b.y; h[6] = (_Float16)b.z; h[7] = (_Float16)b.w;
    *(half8*)&WiP[(size_t)c * 8] = h;
  } else {  // WoP: NKT=8, classes padded to 16
    const int c = t - 98304;  // 0..511
    const int kt = c >> 6, lb = c & 63;
    const int n = lb & 15;
    const int k0 = kt * 32 + (lb >> 4) * 8;
    half8 h;
#pragma unroll
    for (int j = 0; j < 8; ++j) h[j] = (_Float16)((n < 10) ? Wo[n * 256 + k0 + j] : 0.f);
    *(half8*)&WoP[(size_t)c * 8] = h;
  }
}

// ================= fused persistent batch kernel =============================

// byte offset of 4 consecutive halves (col0 must be 4-aligned) in the
// XOR-swizzled row layout: chunk = (col>>3) ^ (row&7), 16B chunks.
__device__ __forceinline__ int lds_off4(int row, int col0) {
  const int chunk = (col0 >> 3) ^ (row & 7);
  return row * 512 + (chunk << 4) + (col0 & 7) * 2;
}

// R4-champion geometry: wave tile 64x32 (mi=4, ni=2), 8 waves, 64-row slab.
// OPERAND-SWAPPED MFMA: mfma(bf, af, acc) — A/B fragment layouts of
// 16x16x32 are symmetric, so this computes the same products with the
// TRANSPOSED C-layout: each lane owns 1 row x 4 consecutive cols
// (quad*4+r) instead of 4 rows x 1 col. Under the swizzle those 4 halves
// are one aligned 8B chunk -> all epilogue LDS traffic becomes b64 ops
// (4x fewer LDS instrs, 4x less swizzle-address VALU), and bias/crm
// epilogue loads become f32x4.
template <int NKT, bool DUAL>
__device__ __forceinline__ void gemm_k(const _Float16* __restrict__ Bp,
                                       const _Float16* A1, const _Float16* A2,
                                       f32x4* acc, int wave, int lane, int quad, int l16) {
  half8 bf[3][2];
  auto loadB = [&](int kt, int s) {
#pragma unroll
    for (int ni = 0; ni < 2; ++ni)
      bf[s][ni] = *(const half8*)&Bp[(((wave * 2 + ni) * NKT + kt) * 64 + lane) * 8];
  };
  loadB(0, 0);
  loadB(1, 1);
#pragma unroll
  for (int kt = 0; kt < NKT; ++kt) {
    const int s = kt % 3;
    if (kt + 2 < NKT) loadB(kt + 2, (kt + 2) % 3);
    const _Float16* Ab = (DUAL && kt >= NKT / 2) ? A2 : A1;
    const int akt = DUAL ? (kt & (NKT / 2 - 1)) : kt;
    half8 af[4];
#pragma unroll
    for (int mi = 0; mi < 4; ++mi) {
      const int row = mi * 16 + l16;
      const int chunk = (akt * 4 + quad) ^ (row & 7);
      af[mi] = *(const half8*)((const char*)Ab + row * 512 + (chunk << 4));
    }
#pragma unroll
    for (int mi = 0; mi < 4; ++mi)
#pragma unroll
      for (int ni = 0; ni < 2; ++ni)
        acc[mi * 2 + ni] = __builtin_amdgcn_mfma_f32_16x16x32_f16(
            bf[s][ni], af[mi], acc[mi * 2 + ni], 0, 0, 0);
  }
}

// 64-row slab, 8 waves, 2 blocks/CU (LDS-bound). launch_bounds(512,2):
// VGPR cap 256 — the established spill-free operating point (WRITE_SIZE
// is the tell; R4 proved 1.3MB clean). uph/r2p return to registers
// (cap 128 forced them out in R0-R3; cap 256 absorbs them).
__global__ __launch_bounds__(512, 2) void k_fused(
    const float* __restrict__ x, const _Float16* __restrict__ WiP,
    const _Float16* __restrict__ PQP, const _Float16* __restrict__ RmP,
    const _Float16* __restrict__ WoP, const float* __restrict__ bi,
    const float* __restrict__ b1, const float* __restrict__ b2,
    const float* __restrict__ b3, const float* __restrict__ b4,
    const float* __restrict__ crm, const float* __restrict__ bo,
    float* __restrict__ out) {
  __shared__ __align__(16) _Float16 A1[64 * 256];
  __shared__ __align__(16) _Float16 A2[64 * 256];
  const int tid = threadIdx.x;
  const int wave = tid >> 6, lane = tid & 63;
  const int quad = lane >> 4, l16 = lane & 15;
  const int m0 = blockIdx.x * 64;

  // ---- stage x: fp32 HBM -> fp16 swizzled LDS (A1) ----
#pragma unroll
  for (int it = 0; it < 8; ++it) {
    const int idx = it * 512 + tid;
    const int row = idx >> 6, c4 = idx & 63;
    const float4 v = *(const float4*)&x[(size_t)(m0 + row) * 256 + c4 * 4];
    const int chunk = (c4 >> 1) ^ (row & 7), part = c4 & 1;
    _Float16* p = (_Float16*)((char*)A1 + row * 512 + (chunk << 4) + (part << 3));
    p[0] = (_Float16)v.x; p[1] = (_Float16)v.y; p[2] = (_Float16)v.z; p[3] = (_Float16)v.w;
  }
  __syncthreads();

  f32x4 acc[8];
  const f32x4 zero = {0.f, 0.f, 0.f, 0.f};
  half4v uph[8], r2p[8];

  // ---- GEMM0: z = x@WiT ; A1 = r1 = z+bi+0.1*b1 ; A2 = r2 = tanh(z+bi) ----
#pragma unroll
  for (int t = 0; t < 8; ++t) acc[t] = zero;
  gemm_k<8, false>(WiP, A1, A1, acc, wave, lane, quad, l16);
  __syncthreads();
#pragma unroll
  for (int ni = 0; ni < 2; ++ni) {
    const int col0 = wave * 32 + ni * 16 + quad * 4;
    const f32x4 bi4 = *(const f32x4*)&bi[col0];
    const f32x4 b14 = *(const f32x4*)&b1[col0];
#pragma unroll
    for (int mi = 0; mi < 4; ++mi) {
      const int row = mi * 16 + l16;
      const int off = lds_off4(row, col0);
      half4v h1, h2;
#pragma unroll
      for (int r = 0; r < 4; ++r) {
        const float z = acc[mi * 2 + ni][r] + bi4[r];
        h1[r] = (_Float16)(z + DTC * b14[r]);
        h2[r] = (_Float16)fast_tanh(z);
      }
      *(half4v*)((char*)A1 + off) = h1;
      *(half4v*)((char*)A2 + off) = h2;
      r2p[mi * 2 + ni] = h2;
    }
  }
  __syncthreads();

  // ---- 4 transport layers (R4-verified flow: v'-GEMM consumes r1_next) ----
#pragma unroll 1
  for (int l = 0; l < 4; ++l) {
    // u' = r1@Pm + r2@Q   (K=512)
#pragma unroll
    for (int t = 0; t < 8; ++t) acc[t] = zero;
    gemm_k<16, true>(PQP + (size_t)l * 131072, A1, A2, acc, wave, lane, quad, l16);
    __syncthreads();
    const float* bn = (l == 0) ? b2 : (l == 1) ? b3 : b4;
#pragma unroll
    for (int ni = 0; ni < 2; ++ni) {
      const int col0 = wave * 32 + ni * 16 + quad * 4;
      f32x4 bn4 = zero;
      if (l < 3) bn4 = DTC * (*(const f32x4*)&bn[col0]);
#pragma unroll
      for (int mi = 0; mi < 4; ++mi) {
        const int row = mi * 16 + l16;
        const int off = lds_off4(row, col0);
        half4v hu, h1;
#pragma unroll
        for (int r = 0; r < 4; ++r) {
          const float u = acc[mi * 2 + ni][r];
          hu[r] = (_Float16)u;
          h1[r] = (_Float16)(u + bn4[r]);
        }
        uph[mi * 2 + ni] = hu;
        *(half4v*)((char*)A1 + off) = h1;   // r1 for next layer / v'-GEMM input
      }
    }
    __syncthreads();
    if (l < 3) {
      // v' = r1_next@Rm - crm - r2 ; new r2 = (v' + 10 tanh u')/11
#pragma unroll
      for (int t = 0; t < 8; ++t) acc[t] = zero;
      gemm_k<8, false>(RmP + (size_t)l * 65536, A1, A1, acc, wave, lane, quad, l16);
#pragma unroll
      for (int ni = 0; ni < 2; ++ni) {
        const int col0 = wave * 32 + ni * 16 + quad * 4;
        const f32x4 cc4 = *(const f32x4*)&crm[l * 256 + col0];
#pragma unroll
        for (int mi = 0; mi < 4; ++mi) {
          const int row = mi * 16 + l16;
          const int off = lds_off4(row, col0);
          half4v nr2;
#pragma unroll
          for (int r = 0; r < 4; ++r) {
            const float vp = acc[mi * 2 + ni][r] - cc4[r] - (float)r2p[mi * 2 + ni][r];
            nr2[r] = (_Float16)((vp + 10.f * fast_tanh((float)uph[mi * 2 + ni][r])) * (1.f / 11.f));
          }
          r2p[mi * 2 + ni] = nr2;
          *(half4v*)((char*)A2 + off) = nr2;
        }
      }
      __syncthreads();
    }
  }

  // ---- head: logits = z@Wo^T + bo (swapped MFMA); softmax ----
  // lane owns batch-row = wave*16 + l16, classes quad*4 + r (4 contiguous).
  if (wave < 4) {
    f32x4 acch = zero;
#pragma unroll
    for (int kt = 0; kt < 8; ++kt) {
      const int row = wave * 16 + l16;
      const int chunk = (kt * 4 + quad) ^ (row & 7);
      const half8 af = *(const half8*)((const char*)A1 + row * 512 + (chunk << 4));
      const half8 bfr = *(const half8*)&WoP[(kt * 64 + lane) * 8];
      acch = __builtin_amdgcn_mfma_f32_16x16x32_f16(bfr, af, acch, 0, 0, 0);
    }
    float v4[4];
    float mx = -3.0e38f;
#pragma unroll
    for (int r = 0; r < 4; ++r) {
      const int cls = quad * 4 + r;
      const float v = acch[r] + ((cls < 10) ? bo[cls] : -3.0e38f);
      v4[r] = v;
      mx = fmaxf(mx, v);
    }
    mx = fmaxf(mx, __shfl_xor(mx, 16, 64));
    mx = fmaxf(mx, __shfl_xor(mx, 32, 64));
    float e4[4], s = 0.f;
#pragma unroll
    for (int r = 0; r < 4; ++r) {
      e4[r] = __expf(v4[r] - mx);
      s += e4[r];
    }
    s += __shfl_xor(s, 16, 64);
    s += __shfl_xor(s, 32, 64);
    const float rs = __builtin_amdgcn_rcpf(s);
    float* op = &out[(size_t)(m0 + wave * 16 + l16) * 10 + quad * 4];
    if (quad < 2) {
      f32x2 p0 = {e4[0] * rs, e4[1] * rs};
      f32x2 p1 = {e4[2] * rs, e4[3] * rs};
      *(f32x2*)op = p0;
      *(f32x2*)(op + 2) = p1;
    } else if (quad == 2) {
      f32x2 p0 = {e4[0] * rs, e4[1] * rs};
      *(f32x2*)op = p0;
    }
  }
}

// ================= launcher ==================================================

extern "C" void kernel_launch(void* const* d_in, const int* in_sizes, int n_in,
                              void* d_out, int out_size, void* d_ws, size_t ws_size,
                              hipStream_t stream) {
  const float* x  = (const float*)d_in[0];
  const float* Wi = (const float*)d_in[1];
  const float* bi = (const float*)d_in[2];
  const float* W[4] = {(const float*)d_in[3], (const float*)d_in[5],
                       (const float*)d_in[7], (const float*)d_in[9]};
  const float* b[4] = {(const float*)d_in[4], (const float*)d_in[6],
                       (const float*)d_in[8], (const float*)d_in[10]};
  const float* Wo = (const float*)d_in[11];
  const float* bo = (const float*)d_in[12];
  float* out = (float*)d_out;

  const int Bsz = in_sizes[0] / 256;  // 32768

  _Float16* hb = (_Float16*)d_ws;
  _Float16* WiP = hb;                   // 65536
  _Float16* WoP = hb + 65536;           // 4096
  _Float16* PQP = hb + 69632;           // 524288
  _Float16* RmP = hb + 593920;          // 196608
  _Float16* Wh  = hb + 790528;          // 262144
  _Float16* Wt  = hb + 1052672;         // 262144
  _Float16* Eh  = hb + 1314816;         // 262144
  _Float16* Ph  = hb + 1576960;         // 262144
  _Float16* Qt  = hb + 1839104;         // 262144
  float* crm = (float*)(hb + 2101248);  // 768 floats

  const dim3 g64(4, 4, 4);
  k_prep<<<387, 256, 0, stream>>>(W[0], W[1], W[2], W[3], b[1], b[2], b[3],
                                  Wh, Wt, crm);
  k_smm3<<<g64, 256, 0, stream>>>(Wh, Wh, nullptr, Eh, 0.01f, 0);  // E = DT^2 W W^T
  k_smm3<<<g64, 256, 0, stream>>>(Eh, Eh, Eh, Ph, 1.0f, 1);        // P = I - E + E^2
  k_smm3<<<g64, 256, 0, stream>>>(Ph, Wt, nullptr, Qt, DTC, 0);    // Qt = 0.1 P@W
  k_pack<<<386, 256, 0, stream>>>(Ph, Qt, Wt, Wi, Wo, PQP, RmP, WiP, WoP);

  k_fused<<<Bsz / 64, 512, 0, stream>>>(x, WiP, PQP, RmP, WoP, bi,
                                        b[0], b[1], b[2], b[3], crm, bo, out);
}